// Round 1
// baseline (1032.712 us; speedup 1.0000x reference)
//
#include <hip/hip_runtime.h>

// ContrastiveLoss: prediction (2,16,32,256,256) fp32, gt (2,32,256,256) int32 (labels 0..50)
// One-pass per-label accumulation of {sum(p), sum(p/||p||), count}, then tiny finalize.
//
// Identity used: cos_v = dot(p_v, m_l)/max(||p_v||*||m_l||, 1e-8)
//              = (p_v/||p_v||) . (m_l/||m_l||)   (clamp never binds: ||m|| ~ 1e-2, ||p|| ~ 4)
// so intra_sum[l] = dot( sum_{v in l} p_v/||p_v|| , m_l ) / ||m_l||.

#define NL   51
#define SROW 33          // 16 sums | 16 nsums | 1 count
#define NREP 4           // replicated LDS tables to cut same-address atomic conflicts
#define TAB  (NREP * NL * SROW)

__global__ __launch_bounds__(256) void cl_pass1(const float* __restrict__ pred,
                                                const int*   __restrict__ gt,
                                                float* __restrict__ gtab) {
    __shared__ float tab[TAB];
    for (int i = threadIdx.x; i < TAB; i += 256) tab[i] = 0.f;
    __syncthreads();

    const unsigned tid  = threadIdx.x;
    const unsigned rep  = tid & (NREP - 1);
    const unsigned base = blockIdx.x * 4096u;      // 1024 blocks * 4096 voxels = 4,194,304

    #pragma unroll 1
    for (int k = 0; k < 16; ++k) {
        unsigned n    = base + k * 256u + tid;     // voxel index over (b, z, y, x)
        unsigned bidx = n >> 21;                   // batch (spatial = 2^21 voxels)
        unsigned sp   = n & ((1u << 21) - 1);
        const float* pb = pred + ((size_t)bidx << 25) + sp;   // bidx*16*2^21 + sp

        float v[16];
        float ss = 0.f;
        #pragma unroll
        for (int c = 0; c < 16; ++c) {
            v[c] = pb[(size_t)c << 21];            // coalesced: lanes contiguous in sp
            ss += v[c] * v[c];
        }
        int   id = gt[n];
        float rn = (ss > 0.f) ? rsqrtf(ss) : 0.f;

        float* row = &tab[(rep * NL + (unsigned)id) * SROW];
        #pragma unroll
        for (int c = 0; c < 16; ++c) unsafeAtomicAdd(&row[c], v[c]);
        #pragma unroll
        for (int c = 0; c < 16; ++c) unsafeAtomicAdd(&row[16 + c], v[c] * rn);
        unsafeAtomicAdd(&row[32], 1.f);
    }
    __syncthreads();

    for (int i = threadIdx.x; i < NL * SROW; i += 256) {
        float t = tab[i] + tab[NL*SROW + i] + tab[2*NL*SROW + i] + tab[3*NL*SROW + i];
        unsafeAtomicAdd(&gtab[i], t);
    }
}

__global__ __launch_bounds__(256) void cl_final(const float* __restrict__ gtab,
                                                float* __restrict__ out) {
    __shared__ float means[NL][16];
    __shared__ float mn[NL];
    __shared__ float cnt[NL];
    __shared__ float cmn[NL - 1][16];
    __shared__ float red[256];
    __shared__ float intra_s;
    const int t = threadIdx.x;

    if (t < NL) cnt[t] = gtab[t * SROW + 32];
    __syncthreads();

    for (int i = t; i < NL * 16; i += 256) {
        int l = i >> 4, c = i & 15;
        means[l][c] = gtab[l * SROW + c] / fmaxf(cnt[l], 1.0f);
    }
    __syncthreads();

    if (t < NL) {
        float s = 0.f;
        #pragma unroll
        for (int c = 0; c < 16; ++c) s += means[t][c] * means[t][c];
        mn[t] = sqrtf(s);
    }
    __syncthreads();

    // intra_per_label for labels 1..50
    float intra = 0.f;
    if (t < NL - 1) {
        int l = t + 1;
        float d = 0.f;
        #pragma unroll
        for (int c = 0; c < 16; ++c) d += gtab[l * SROW + 16 + c] * means[l][c];
        float isum = (mn[l] > 0.f) ? d / mn[l] : 0.f;
        intra = isum / fmaxf(cnt[l], 1.0f);
    }
    red[t] = intra;
    __syncthreads();
    for (int s = 128; s > 0; s >>= 1) { if (t < s) red[t] += red[t + s]; __syncthreads(); }
    if (t == 0) intra_s = red[0] / (float)(NL - 1);

    // normalized means for labels 1..50
    for (int i = t; i < (NL - 1) * 16; i += 256) {
        int l = (i >> 4) + 1, c = i & 15;
        cmn[i >> 4][c] = means[l][c] / fmaxf(mn[l], 1e-8f);
    }
    __syncthreads();

    // 1225 upper-triangle pairs among 50 labels
    float acc = 0.f;
    int k = 0;
    for (int i = 0; i < NL - 2; ++i)
        for (int j = i + 1; j < NL - 1; ++j) {
            if ((k & 255) == t) {
                float d = 0.f;
                #pragma unroll
                for (int c = 0; c < 16; ++c) d += cmn[i][c] * cmn[j][c];
                acc += fminf(fmaxf(d, 0.f), 1.f);
            }
            ++k;
        }
    red[t] = acc;
    __syncthreads();
    for (int s = 128; s > 0; s >>= 1) { if (t < s) red[t] += red[t + s]; __syncthreads(); }
    if (t == 0) out[0] = red[0] / 1225.f - intra_s;
}

extern "C" void kernel_launch(void* const* d_in, const int* in_sizes, int n_in,
                              void* d_out, int out_size, void* d_ws, size_t ws_size,
                              hipStream_t stream) {
    const float* pred = (const float*)d_in[0];
    const int*   gt   = (const int*)d_in[1];
    float* gtab = (float*)d_ws;

    hipMemsetAsync(gtab, 0, NL * SROW * sizeof(float), stream);
    cl_pass1<<<1024, 256, 0, stream>>>(pred, gt, gtab);
    cl_final<<<1, 256, 0, stream>>>(gtab, (float*)d_out);
}